// Round 1
// baseline (186.319 us; speedup 1.0000x reference)
//
#include <hip/hip_runtime.h>
#include <hip/hip_bf16.h>

#define NPRI 10647
#define BB 16
#define LL 50

// anchors: level0 S=13, level1 S=26, level2 S=52
__device__ __constant__ int c_AW[3][3] = {{116,156,373},{30,62,59},{10,16,33}};
__device__ __constant__ int c_AH[3][3] = {{90,198,326},{61,45,119},{23,30,23}};
// 1 / (B*A*S*S) per level
__device__ __constant__ double c_wObj[3] = {1.0/8112.0, 1.0/32448.0, 1.0/129792.0};

__device__ inline void decode_prior(int n, int& level, int& S, int& ii, int& jj, int& aa) {
    int nn;
    if (n < 507)       { level = 0; S = 13; nn = n; }
    else if (n < 2535) { level = 1; S = 26; nn = n - 507; }
    else               { level = 2; S = 52; nn = n - 2535; }
    aa = nn % 3; int c = nn / 3; jj = c % S; ii = c / S;
}

// ---------------------------------------------------------------- init
__global__ __launch_bounds__(256) void init_kernel(
    float4* __restrict__ priorsA, float* __restrict__ priorsB,
    int* __restrict__ winner, unsigned char* __restrict__ supp,
    int* __restrict__ idxArr, double* __restrict__ accum) {
    int i = blockIdx.x * 256 + threadIdx.x;
    if (i < BB * NPRI) { winner[i] = -1; supp[i] = 0; }
    if (i < BB * LL) idxArr[i] = -1;
    if (i < 3) accum[i] = 0.0;
    if (i < NPRI) {
        int level, S, ii, jj, aa;
        decode_prior(i, level, S, ii, jj, aa);
        // match numpy: python-double math, then fp32 cast
        double w  = (double)c_AW[level][aa] / 416.0;
        double h  = (double)c_AH[level][aa] / 416.0;
        double cx = ((double)jj + 0.5) / (double)S;
        double cy = ((double)ii + 0.5) / (double)S;
        float px = (float)(cx - 0.5 * w);
        float py = (float)(cy - 0.5 * h);
        float pw = (float)w, ph = (float)h;
        priorsA[i] = make_float4(px, py, __fadd_rn(px, pw), __fadd_rn(py, ph));
        priorsB[i] = __fmul_rn(pw, ph);
    }
}

// ---------------------------------------------------------------- assign (one block per (b,l))
__global__ __launch_bounds__(256) void assign_kernel(
    const float* __restrict__ labels, const float4* __restrict__ priorsA,
    const float* __restrict__ priorsB, int* __restrict__ winner,
    unsigned char* __restrict__ supp, int* __restrict__ idxArr,
    float4* __restrict__ tcoord) {
    __shared__ float s_iou[NPRI];   // 42.6 KB
    __shared__ float s_red[256];
    __shared__ int   s_cnt[257];

    int b = blockIdx.x / LL, l = blockIdx.x % LL;
    const float* lab = labels + (b * LL + l) * 5;
    float cls = lab[0];
    if (cls < 0.0f) return;   // uniform per block: safe

    float bx = lab[1], by = lab[2], bw = lab[3], bh = lab[4];
    float bxe  = __fadd_rn(bx, bw), bye = __fadd_rn(by, bh);
    float bwbh = __fmul_rn(bw, bh);
    int tid = threadIdx.x;

    float lmax = -3.0e38f;
    for (int n = tid; n < NPRI; n += 256) {
        float4 p   = priorsA[n];       // (px, py, px+pw, py+ph)
        float pwph = priorsB[n];
        float ix = fmaxf(p.x, bx), iy = fmaxf(p.y, by);
        float ax = fminf(p.z, bxe), ay = fminf(p.w, bye);
        float iw = fmaxf(__fsub_rn(ax, ix), 0.0f);
        float ih = fmaxf(__fsub_rn(ay, iy), 0.0f);
        float inter = __fmul_rn(iw, ih);
        float denom = __fsub_rn(__fadd_rn(pwph, bwbh), inter);
        float iou = __fdiv_rn(inter, denom);
        s_iou[n] = iou;
        lmax = fmaxf(lmax, iou);
        if (iou >= 0.5f) supp[b * NPRI + n] = 1;  // benign race: all write 1
    }
    s_red[tid] = lmax;
    __syncthreads();
    for (int s = 128; s > 0; s >>= 1) {
        if (tid < s) s_red[tid] = fmaxf(s_red[tid], s_red[tid + s]);
        __syncthreads();
    }
    float m = s_red[0];

    // ordered tie scan over contiguous chunks (replicates cumsum/rank logic)
    const int CH = 42;   // 256*42 >= NPRI
    int start = tid * CH;
    int end   = min(start + CH, NPRI);
    int cnt = 0;
    for (int n = start; n < end; ++n) cnt += (s_iou[n] == m) ? 1 : 0;
    s_cnt[tid] = cnt;
    __syncthreads();
    if (tid == 0) {
        int acc = 0;
        for (int t = 0; t < 256; ++t) { int c = s_cnt[t]; s_cnt[t] = acc; acc += c; }
        s_cnt[256] = acc;
    }
    __syncthreads();
    int k    = s_cnt[256];
    int rank = (k - 1) / 2 + 1;
    int pre  = s_cnt[tid];
    if (pre < rank && rank <= pre + cnt) {
        int r = rank - pre;
        int sel = -1;
        for (int n = start; n < end; ++n) {
            if (s_iou[n] == m && --r == 0) { sel = n; break; }
        }
        int level, S, ii, jj, aa;
        decode_prior(sel, level, S, ii, jj, aa);
        float Sf = (float)S, colf = (float)jj, rowf = (float)ii;
        float awf = (float)c_AW[level][aa], ahf = (float)c_AH[level][aa];
        float dx = __fsub_rn(__fmul_rn(__fadd_rn(bx, __fmul_rn(0.5f, bw)), Sf), colf);
        float dy = __fsub_rn(__fmul_rn(__fadd_rn(by, __fmul_rn(0.5f, bh)), Sf), rowf);
        dx = fminf(fmaxf(dx, 1e-6f), 0.999999f);
        dy = fminf(fmaxf(dy, 1e-6f), 0.999999f);
        float t0 = logf(__fdiv_rn(dx, __fsub_rn(1.0f, dx)));
        float t1 = logf(__fdiv_rn(dy, __fsub_rn(1.0f, dy)));
        float t2 = logf(__fdiv_rn(__fmul_rn(bw, 416.0f), awf));
        float t3 = logf(__fdiv_rn(__fmul_rn(bh, 416.0f), ahf));
        int gi = b * LL + l;
        tcoord[gi] = make_float4(t0, t1, t2, t3);
        idxArr[gi] = sel;
        atomicMax(&winner[b * NPRI + sel], gi);   // segment_max over g
    }
}

// ---------------------------------------------------------------- loss (one thread per (b,n))
__global__ __launch_bounds__(256) void loss_kernel(
    const float* __restrict__ o0, const float* __restrict__ o1, const float* __restrict__ o2,
    const float* __restrict__ labels, const int* __restrict__ winner,
    const unsigned char* __restrict__ supp, const int* __restrict__ idxArr,
    const float4* __restrict__ tcoord, double* __restrict__ accum) {
    int tid = threadIdx.x;
    int e = blockIdx.x * 256 + tid;
    double aObj = 0.0, aCoord = 0.0, aClass = 0.0;
    if (e < BB * NPRI) {
        int b = e / NPRI, n = e % NPRI;
        int level, S, ii, jj, aa;
        decode_prior(n, level, S, ii, jj, aa);
        const float* out = (level == 0) ? o0 : ((level == 1) ? o1 : o2);
        int SS2 = S * S;
        const float* cell = out + (size_t)b * 255 * SS2 + ii * S + jj; // +ch*SS2 per channel
        int w = winner[e];
        bool chosen = (w >= 0);
        bool om = chosen || (supp[e] == 0);
        double wObj = c_wObj[level];
        if (om) {   // masked-out entries contribute exactly 0 in the reference
            float x = cell[(aa * 85 + 4) * SS2];
            float p = 1.0f / (1.0f + expf(-x));
            float t = chosen ? 1.0f : 0.0f;
            float lp = fmaxf(logf(p), -100.0f);
            float lq = fmaxf(logf(1.0f - p), -100.0f);
            aObj = -(double)(t * lp + (1.0f - t) * lq) * wObj;
        }
        if (chosen) {
            float4 ct = tcoord[b * LL + (w % LL)];
            float ctk[4] = {ct.x, ct.y, ct.z, ct.w};
            double sc = 0.0;
            for (int kk = 0; kk < 4; ++kk) {
                float x = cell[(aa * 85 + kk) * SS2];
                float d = __fsub_rn(x, ctk[kk]);
                sc += (double)__fmul_rn(d, d);
            }
            aCoord = sc * (wObj * 0.25);
            // rebuild multi-hot class target from all valid labels assigned here
            unsigned m0 = 0, m1 = 0, m2 = 0;
            for (int l2 = 0; l2 < LL; ++l2) {
                if (idxArr[b * LL + l2] == n) {
                    int cc = (int)labels[(b * LL + l2) * 5];
                    if (cc < 32)      m0 |= 1u << cc;
                    else if (cc < 64) m1 |= 1u << (cc - 32);
                    else              m2 |= 1u << (cc - 64);
                }
            }
            double scl = 0.0;
            for (int cc = 0; cc < 80; ++cc) {
                float x = cell[(aa * 85 + 5 + cc) * SS2];
                float p = 1.0f / (1.0f + expf(-x));
                unsigned bit = (cc < 32) ? (m0 >> cc)
                             : ((cc < 64) ? (m1 >> (cc - 32)) : (m2 >> (cc - 64)));
                float t = (bit & 1u) ? 1.0f : 0.0f;
                float lp = fmaxf(logf(p), -100.0f);
                float lq = fmaxf(logf(1.0f - p), -100.0f);
                scl += (double)(-(t * lp + (1.0f - t) * lq));
            }
            aClass = scl * (wObj * 0.0125);
        }
    }
    __shared__ double sred[256];
    sred[tid] = aObj; __syncthreads();
    for (int s = 128; s > 0; s >>= 1) { if (tid < s) sred[tid] += sred[tid + s]; __syncthreads(); }
    if (tid == 0) atomicAdd(&accum[0], sred[0]);
    __syncthreads();
    sred[tid] = aCoord; __syncthreads();
    for (int s = 128; s > 0; s >>= 1) { if (tid < s) sred[tid] += sred[tid + s]; __syncthreads(); }
    if (tid == 0) atomicAdd(&accum[1], sred[0]);
    __syncthreads();
    sred[tid] = aClass; __syncthreads();
    for (int s = 128; s > 0; s >>= 1) { if (tid < s) sred[tid] += sred[tid + s]; __syncthreads(); }
    if (tid == 0) atomicAdd(&accum[2], sred[0]);
}

// ---------------------------------------------------------------- finalize
__global__ void finalize_kernel(const double* __restrict__ accum, float* __restrict__ out) {
    int t = threadIdx.x;
    if (t < 3) out[t] = (float)accum[t];
}

extern "C" void kernel_launch(void* const* d_in, const int* in_sizes, int n_in,
                              void* d_out, int out_size, void* d_ws, size_t ws_size,
                              hipStream_t stream) {
    const float* o0     = (const float*)d_in[0];
    const float* o1     = (const float*)d_in[1];
    const float* o2     = (const float*)d_in[2];
    const float* labels = (const float*)d_in[3];

    char* ws = (char*)d_ws;
    float4*        priorsA = (float4*)(ws);                 // 10647*16 = 170352
    float*         priorsB = (float*) (ws + 170352);        // 42588  -> 212940
    int*           winner  = (int*)   (ws + 212940);        // 681408 -> 894348
    unsigned char* supp    = (unsigned char*)(ws + 894348); // 170352 -> 1064700
    int*           idxArr  = (int*)   (ws + 1064700);       // 3200   -> 1067900
    float4*        tcoord  = (float4*)(ws + 1067904);       // 12800  -> 1080704
    double*        accum   = (double*)(ws + 1080704);       // 24     -> 1080728

    int initBlocks = (BB * NPRI + 255) / 256;
    init_kernel<<<initBlocks, 256, 0, stream>>>(priorsA, priorsB, winner, supp, idxArr, accum);
    assign_kernel<<<BB * LL, 256, 0, stream>>>(labels, priorsA, priorsB, winner, supp, idxArr, tcoord);
    loss_kernel<<<(BB * NPRI + 255) / 256, 256, 0, stream>>>(o0, o1, o2, labels, winner, supp, idxArr, tcoord, accum);
    finalize_kernel<<<1, 64, 0, stream>>>(accum, (float*)d_out);
}

// Round 2
// 128.803 us; speedup vs baseline: 1.4465x; 1.4465x over previous
//
#include <hip/hip_runtime.h>
#include <hip/hip_bf16.h>

#define NPRI 10647
#define BB 16
#define LL 50
#define OBJ_BLOCKS 666   // ceil(16*10647 / 256)

// anchors: level0 S=13, level1 S=26, level2 S=52
__device__ __constant__ int c_AW[3][3] = {{116,156,373},{30,62,59},{10,16,33}};
__device__ __constant__ int c_AH[3][3] = {{90,198,326},{61,45,119},{23,30,23}};
// 1 / (B*A*S*S) per level
__device__ __constant__ double c_wObj[3] = {1.0/8112.0, 1.0/32448.0, 1.0/129792.0};

__device__ inline void decode_prior(int n, int& level, int& S, int& ii, int& jj, int& aa) {
    int nn;
    if (n < 507)       { level = 0; S = 13; nn = n; }
    else if (n < 2535) { level = 1; S = 26; nn = n - 507; }
    else               { level = 2; S = 52; nn = n - 2535; }
    aa = nn % 3; int c = nn / 3; jj = c % S; ii = c / S;
}

// ---------------------------------------------------------------- init
__global__ __launch_bounds__(256) void init_kernel(
    float4* __restrict__ priorsA, float* __restrict__ priorsB,
    int* __restrict__ winner, unsigned char* __restrict__ supp,
    int* __restrict__ idxArr) {
    int i = blockIdx.x * 256 + threadIdx.x;
    if (i < BB * NPRI) { winner[i] = -1; supp[i] = 0; }
    if (i < BB * LL) idxArr[i] = -1;
    if (i < NPRI) {
        int level, S, ii, jj, aa;
        decode_prior(i, level, S, ii, jj, aa);
        // match numpy: python-double math, then fp32 cast
        double w  = (double)c_AW[level][aa] / 416.0;
        double h  = (double)c_AH[level][aa] / 416.0;
        double cx = ((double)jj + 0.5) / (double)S;
        double cy = ((double)ii + 0.5) / (double)S;
        float px = (float)(cx - 0.5 * w);
        float py = (float)(cy - 0.5 * h);
        float pw = (float)w, ph = (float)h;
        priorsA[i] = make_float4(px, py, __fadd_rn(px, pw), __fadd_rn(py, ph));
        priorsB[i] = __fmul_rn(pw, ph);
    }
}

// ---------------------------------------------------------------- assign (one block per (b,l))
__global__ __launch_bounds__(256) void assign_kernel(
    const float* __restrict__ labels, const float4* __restrict__ priorsA,
    const float* __restrict__ priorsB, int* __restrict__ winner,
    unsigned char* __restrict__ supp, int* __restrict__ idxArr,
    float4* __restrict__ tcoord) {
    __shared__ float s_iou[NPRI];   // 42.6 KB
    __shared__ float s_red[256];
    __shared__ int   s_cnt[257];

    int b = blockIdx.x / LL, l = blockIdx.x % LL;
    const float* lab = labels + (b * LL + l) * 5;
    float cls = lab[0];
    if (cls < 0.0f) return;   // uniform per block: safe

    float bx = lab[1], by = lab[2], bw = lab[3], bh = lab[4];
    float bxe  = __fadd_rn(bx, bw), bye = __fadd_rn(by, bh);
    float bwbh = __fmul_rn(bw, bh);
    int tid = threadIdx.x;

    float lmax = -3.0e38f;
    for (int n = tid; n < NPRI; n += 256) {
        float4 p   = priorsA[n];       // (px, py, px+pw, py+ph)
        float pwph = priorsB[n];
        float ix = fmaxf(p.x, bx), iy = fmaxf(p.y, by);
        float ax = fminf(p.z, bxe), ay = fminf(p.w, bye);
        float iw = fmaxf(__fsub_rn(ax, ix), 0.0f);
        float ih = fmaxf(__fsub_rn(ay, iy), 0.0f);
        float inter = __fmul_rn(iw, ih);
        float denom = __fsub_rn(__fadd_rn(pwph, bwbh), inter);
        float iou = __fdiv_rn(inter, denom);
        s_iou[n] = iou;
        lmax = fmaxf(lmax, iou);
        if (iou >= 0.5f) supp[b * NPRI + n] = 1;  // benign race: all write 1
    }
    s_red[tid] = lmax;
    __syncthreads();
    for (int s = 128; s > 0; s >>= 1) {
        if (tid < s) s_red[tid] = fmaxf(s_red[tid], s_red[tid + s]);
        __syncthreads();
    }
    float m = s_red[0];

    // ordered tie scan over contiguous chunks (replicates cumsum/rank logic)
    const int CH = 42;   // 256*42 >= NPRI
    int start = tid * CH;
    int end   = min(start + CH, NPRI);
    int cnt = 0;
    for (int n = start; n < end; ++n) cnt += (s_iou[n] == m) ? 1 : 0;
    s_cnt[tid] = cnt;
    __syncthreads();
    if (tid == 0) {
        int acc = 0;
        for (int t = 0; t < 256; ++t) { int c = s_cnt[t]; s_cnt[t] = acc; acc += c; }
        s_cnt[256] = acc;
    }
    __syncthreads();
    int k    = s_cnt[256];
    int rank = (k - 1) / 2 + 1;
    int pre  = s_cnt[tid];
    if (pre < rank && rank <= pre + cnt) {
        int r = rank - pre;
        int sel = -1;
        for (int n = start; n < end; ++n) {
            if (s_iou[n] == m && --r == 0) { sel = n; break; }
        }
        int level, S, ii, jj, aa;
        decode_prior(sel, level, S, ii, jj, aa);
        float Sf = (float)S, colf = (float)jj, rowf = (float)ii;
        float awf = (float)c_AW[level][aa], ahf = (float)c_AH[level][aa];
        float dx = __fsub_rn(__fmul_rn(__fadd_rn(bx, __fmul_rn(0.5f, bw)), Sf), colf);
        float dy = __fsub_rn(__fmul_rn(__fadd_rn(by, __fmul_rn(0.5f, bh)), Sf), rowf);
        dx = fminf(fmaxf(dx, 1e-6f), 0.999999f);
        dy = fminf(fmaxf(dy, 1e-6f), 0.999999f);
        float t0 = logf(__fdiv_rn(dx, __fsub_rn(1.0f, dx)));
        float t1 = logf(__fdiv_rn(dy, __fsub_rn(1.0f, dy)));
        float t2 = logf(__fdiv_rn(__fmul_rn(bw, 416.0f), awf));
        float t3 = logf(__fdiv_rn(__fmul_rn(bh, 416.0f), ahf));
        int gi = b * LL + l;
        tcoord[gi] = make_float4(t0, t1, t2, t3);
        idxArr[gi] = sel;
        atomicMax(&winner[b * NPRI + sel], gi);   // segment_max over g
    }
}

// ---------------------------------------------------------------- obj loss (one thread per (b,n))
__global__ __launch_bounds__(256) void obj_kernel(
    const float* __restrict__ o0, const float* __restrict__ o1, const float* __restrict__ o2,
    const int* __restrict__ winner, const unsigned char* __restrict__ supp,
    double* __restrict__ pObj) {
    int tid = threadIdx.x;
    int e = blockIdx.x * 256 + tid;
    double a = 0.0;
    if (e < BB * NPRI) {
        int b = e / NPRI, n = e % NPRI;
        int level, S, ii, jj, aa;
        decode_prior(n, level, S, ii, jj, aa);
        const float* out = (level == 0) ? o0 : ((level == 1) ? o1 : o2);
        int SS2 = S * S;
        float x = out[(size_t)b * 255 * SS2 + (aa * 85 + 4) * SS2 + ii * S + jj];
        bool chosen = (winner[e] >= 0);
        bool om = chosen || (supp[e] == 0);
        if (om) {   // masked-out entries contribute exactly 0 in the reference
            float p = 1.0f / (1.0f + expf(-x));
            float t = chosen ? 1.0f : 0.0f;
            float lp = fmaxf(logf(p), -100.0f);
            float lq = fmaxf(logf(1.0f - p), -100.0f);
            a = -(double)(t * lp + (1.0f - t) * lq) * c_wObj[level];
        }
    }
    __shared__ double sred[256];
    sred[tid] = a; __syncthreads();
    for (int s = 128; s > 0; s >>= 1) { if (tid < s) sred[tid] += sred[tid + s]; __syncthreads(); }
    if (tid == 0) pObj[blockIdx.x] = sred[0];
}

// ---------------------------------------------------------------- coord+class loss (one block per label gi)
// Only the winning label per prior computes; the 84 channel loads go out
// lane-parallel (one channel per thread) instead of a serial loop.
__global__ __launch_bounds__(128) void chosen_kernel(
    const float* __restrict__ o0, const float* __restrict__ o1, const float* __restrict__ o2,
    const float* __restrict__ labels, const int* __restrict__ winner,
    const int* __restrict__ idxArr, const float4* __restrict__ tcoord,
    double* __restrict__ pCoord, double* __restrict__ pClass) {
    int gi = blockIdx.x;
    int tid = threadIdx.x;
    int b = gi / LL;
    int sel = idxArr[gi];
    bool active = (sel >= 0) && (winner[b * NPRI + sel] == gi);
    if (!active) {
        if (tid == 0) { pCoord[gi] = 0.0; pClass[gi] = 0.0; }
        return;
    }
    __shared__ int   s_idx[LL];
    __shared__ float s_cls[LL];
    __shared__ double s_red[128];
    if (tid < LL) {
        s_idx[tid] = idxArr[b * LL + tid];
        s_cls[tid] = labels[(b * LL + tid) * 5];
    }
    __syncthreads();

    int level, S, ii, jj, aa;
    decode_prior(sel, level, S, ii, jj, aa);
    int SS2 = S * S;
    const float* out = (level == 0) ? o0 : ((level == 1) ? o1 : o2);
    const float* base = out + (size_t)b * 255 * SS2 + aa * 85 * SS2 + ii * S + jj;
    double wObj = c_wObj[level];

    double val = 0.0;
    if (tid < 4) {                    // coord channels 0..3
        float4 ct = tcoord[gi];
        float ctk = (tid == 0) ? ct.x : (tid == 1) ? ct.y : (tid == 2) ? ct.z : ct.w;
        float x = base[tid * SS2];
        float d = __fsub_rn(x, ctk);
        val = (double)__fmul_rn(d, d) * (wObj * 0.25);
    } else if (tid >= 5 && tid < 85) { // class channels 5..84 -> cc = tid-5
        int cc = tid - 5;
        float x = base[tid * SS2];
        float t = 0.0f;
        for (int l2 = 0; l2 < LL; ++l2)
            if (s_idx[l2] == sel && (int)s_cls[l2] == cc) t = 1.0f;
        float p = 1.0f / (1.0f + expf(-x));
        float lp = fmaxf(logf(p), -100.0f);
        float lq = fmaxf(logf(1.0f - p), -100.0f);
        val = -(double)(t * lp + (1.0f - t) * lq) * (wObj * 0.0125);
    }

    s_red[tid] = (tid < 4) ? val : 0.0;
    __syncthreads();
    for (int s = 64; s > 0; s >>= 1) { if (tid < s) s_red[tid] += s_red[tid + s]; __syncthreads(); }
    if (tid == 0) pCoord[gi] = s_red[0];
    __syncthreads();
    s_red[tid] = (tid >= 5 && tid < 85) ? val : 0.0;
    __syncthreads();
    for (int s = 64; s > 0; s >>= 1) { if (tid < s) s_red[tid] += s_red[tid + s]; __syncthreads(); }
    if (tid == 0) pClass[gi] = s_red[0];
}

// ---------------------------------------------------------------- finalize (single block, no atomics anywhere)
__global__ __launch_bounds__(256) void finalize_kernel(
    const double* __restrict__ pObj, const double* __restrict__ pCoord,
    const double* __restrict__ pClass, float* __restrict__ out) {
    int tid = threadIdx.x;
    double sO = 0.0, sC = 0.0, sK = 0.0;
    for (int i = tid; i < OBJ_BLOCKS; i += 256) sO += pObj[i];
    for (int i = tid; i < BB * LL; i += 256) { sC += pCoord[i]; sK += pClass[i]; }
    __shared__ double r0[256], r1[256], r2[256];
    r0[tid] = sO; r1[tid] = sC; r2[tid] = sK;
    __syncthreads();
    for (int s = 128; s > 0; s >>= 1) {
        if (tid < s) { r0[tid] += r0[tid + s]; r1[tid] += r1[tid + s]; r2[tid] += r2[tid + s]; }
        __syncthreads();
    }
    if (tid == 0) { out[0] = (float)r0[0]; out[1] = (float)r1[0]; out[2] = (float)r2[0]; }
}

extern "C" void kernel_launch(void* const* d_in, const int* in_sizes, int n_in,
                              void* d_out, int out_size, void* d_ws, size_t ws_size,
                              hipStream_t stream) {
    const float* o0     = (const float*)d_in[0];
    const float* o1     = (const float*)d_in[1];
    const float* o2     = (const float*)d_in[2];
    const float* labels = (const float*)d_in[3];

    char* ws = (char*)d_ws;
    float4*        priorsA = (float4*)(ws);                 // 170352
    float*         priorsB = (float*) (ws + 170352);        // -> 212940
    int*           winner  = (int*)   (ws + 212940);        // -> 894348
    unsigned char* supp    = (unsigned char*)(ws + 894348); // -> 1064700
    int*           idxArr  = (int*)   (ws + 1064700);       // -> 1067900
    float4*        tcoord  = (float4*)(ws + 1067904);       // -> 1080704
    double*        pObj    = (double*)(ws + 1080704);       // 666*8  -> 1086032
    double*        pCoord  = (double*)(ws + 1086032);       // 800*8  -> 1092432
    double*        pClass  = (double*)(ws + 1092432);       // 800*8  -> 1098832

    int initBlocks = (BB * NPRI + 255) / 256;
    init_kernel<<<initBlocks, 256, 0, stream>>>(priorsA, priorsB, winner, supp, idxArr);
    assign_kernel<<<BB * LL, 256, 0, stream>>>(labels, priorsA, priorsB, winner, supp, idxArr, tcoord);
    obj_kernel<<<OBJ_BLOCKS, 256, 0, stream>>>(o0, o1, o2, winner, supp, pObj);
    chosen_kernel<<<BB * LL, 128, 0, stream>>>(o0, o1, o2, labels, winner, idxArr, tcoord, pCoord, pClass);
    finalize_kernel<<<1, 256, 0, stream>>>(pObj, pCoord, pClass, (float*)d_out);
}

// Round 3
// 126.989 us; speedup vs baseline: 1.4672x; 1.0143x over previous
//
#include <hip/hip_runtime.h>

#define NPRI 10647
#define BB 16
#define LL 50
#define OBJ_BLOCKS 666          // ceil(16*10647 / 256)
#define CHO_BLOCKS (BB * LL)    // 800
#define TOT_BLOCKS (OBJ_BLOCKS + CHO_BLOCKS)

// All anchor-derived constants folded at COMPILE TIME in double, matching
// numpy's python-float math exactly. 0.5*(aw/416.0) == exact halving of the
// rounded double quotient (power-of-2 scale commutes with rounding).
__device__ __constant__ double c_hw[3][3] = {
    {0.5*(116.0/416.0), 0.5*(156.0/416.0), 0.5*(373.0/416.0)},
    {0.5*( 30.0/416.0), 0.5*( 62.0/416.0), 0.5*( 59.0/416.0)},
    {0.5*( 10.0/416.0), 0.5*( 16.0/416.0), 0.5*( 33.0/416.0)}};
__device__ __constant__ double c_hh[3][3] = {
    {0.5*( 90.0/416.0), 0.5*(198.0/416.0), 0.5*(326.0/416.0)},
    {0.5*( 61.0/416.0), 0.5*( 45.0/416.0), 0.5*(119.0/416.0)},
    {0.5*( 23.0/416.0), 0.5*( 30.0/416.0), 0.5*( 23.0/416.0)}};
__device__ __constant__ float c_pwf[3][3] = {
    {(float)(116.0/416.0), (float)(156.0/416.0), (float)(373.0/416.0)},
    {(float)( 30.0/416.0), (float)( 62.0/416.0), (float)( 59.0/416.0)},
    {(float)( 10.0/416.0), (float)( 16.0/416.0), (float)( 33.0/416.0)}};
__device__ __constant__ float c_phf[3][3] = {
    {(float)( 90.0/416.0), (float)(198.0/416.0), (float)(326.0/416.0)},
    {(float)( 61.0/416.0), (float)( 45.0/416.0), (float)(119.0/416.0)},
    {(float)( 23.0/416.0), (float)( 30.0/416.0), (float)( 23.0/416.0)}};
__device__ __constant__ float c_awf[3][3] = {{116,156,373},{30,62,59},{10,16,33}};
__device__ __constant__ float c_ahf[3][3] = {{90,198,326},{61,45,119},{23,30,23}};
// 1 / (B*A*S*S) per level
__device__ __constant__ double c_wObj[3] = {1.0/8112.0, 1.0/32448.0, 1.0/129792.0};

// per-branch constant divisors -> compiler emits magic-mul, no runtime idiv
__device__ inline void decode_prior(int n, int& level, int& S, int& ii, int& jj,
                                    int& aa, int& off) {
    if (n < 507)        { level = 0; S = 13; int c = n / 3;            aa = n - 3*c;            jj = c % 13; ii = c / 13; off = 0;  }
    else if (n < 2535)  { level = 1; S = 26; int nn = n - 507;  int c = nn / 3; aa = nn - 3*c; jj = c % 26; ii = c / 26; off = 13; }
    else                { level = 2; S = 52; int nn = n - 2535; int c = nn / 3; aa = nn - 3*c; jj = c % 52; ii = c / 52; off = 39; }
}

// ---------------------------------------------------------------- assign (one block per (b,l))
// No global prior table, no winner/supp arrays, no atomics, no init kernel.
__global__ __launch_bounds__(256) void assign_kernel(
    const float* __restrict__ labels, int* __restrict__ idxArr,
    float4* __restrict__ tcoord) {
    __shared__ double s_cx[91];     // (idx+0.5)/S for S in {13,26,52}
    __shared__ float  s_iou[NPRI];  // 42.6 KB
    __shared__ float  s_red[256];
    __shared__ int    s_cnt[256];

    int tid = threadIdx.x;
    int gi  = blockIdx.x;
    const float* lab = labels + gi * 5;
    float cls = lab[0];
    if (tid == 0) idxArr[gi] = -1;
    if (cls < 0.0f) return;   // uniform per block, before any __syncthreads

    if (tid < 91) {   // double-precision center table, matching numpy
        int S, idx;
        if (tid < 13)      { S = 13; idx = tid; }
        else if (tid < 39) { S = 26; idx = tid - 13; }
        else               { S = 52; idx = tid - 39; }
        s_cx[tid] = ((double)idx + 0.5) / (double)S;
    }

    float bx = lab[1], by = lab[2], bw = lab[3], bh = lab[4];
    float bxe  = __fadd_rn(bx, bw), bye = __fadd_rn(by, bh);
    float bwbh = __fmul_rn(bw, bh);
    __syncthreads();

    float lmax = -3.0e38f;
    for (int n = tid; n < NPRI; n += 256) {
        int level, S, ii, jj, aa, off;
        decode_prior(n, level, S, ii, jj, aa, off);
        float px  = (float)(s_cx[off + jj] - c_hw[level][aa]);
        float py  = (float)(s_cx[off + ii] - c_hh[level][aa]);
        float pwf = c_pwf[level][aa], phf = c_phf[level][aa];
        float pxe = __fadd_rn(px, pwf), pye = __fadd_rn(py, phf);
        float pwph = __fmul_rn(pwf, phf);
        float ix = fmaxf(px, bx), iy = fmaxf(py, by);
        float ax = fminf(pxe, bxe), ay = fminf(pye, bye);
        float iw = fmaxf(__fsub_rn(ax, ix), 0.0f);
        float ih = fmaxf(__fsub_rn(ay, iy), 0.0f);
        float inter = __fmul_rn(iw, ih);
        float denom = __fsub_rn(__fadd_rn(pwph, bwbh), inter);
        float iou = __fdiv_rn(inter, denom);
        s_iou[n] = iou;
        lmax = fmaxf(lmax, iou);
    }
    s_red[tid] = lmax;
    __syncthreads();
    for (int s = 128; s > 0; s >>= 1) {
        if (tid < s) s_red[tid] = fmaxf(s_red[tid], s_red[tid + s]);
        __syncthreads();
    }
    float m = s_red[0];

    // tie count per contiguous chunk (index order)
    const int CH = 42;   // 256*42 >= NPRI
    int start = tid * CH;
    int end   = min(start + CH, NPRI);
    int cnt = 0;
    for (int n = start; n < end; ++n) cnt += (s_iou[n] == m) ? 1 : 0;

    // parallel inclusive scan (Hillis-Steele, 8 steps) — replaces serial tid0 loop
    s_cnt[tid] = cnt;
    __syncthreads();
    for (int d = 1; d < 256; d <<= 1) {
        int add = (tid >= d) ? s_cnt[tid - d] : 0;
        __syncthreads();
        s_cnt[tid] += add;
        __syncthreads();
    }
    int k    = s_cnt[255];
    int rank = (k - 1) / 2 + 1;
    int pre  = s_cnt[tid] - cnt;   // exclusive prefix

    if (pre < rank && rank <= pre + cnt) {
        int r = rank - pre;
        int sel = -1;
        for (int n = start; n < end; ++n)
            if (s_iou[n] == m && --r == 0) { sel = n; break; }
        int level, S, ii, jj, aa, off;
        decode_prior(sel, level, S, ii, jj, aa, off);
        float Sf = (float)S, colf = (float)jj, rowf = (float)ii;
        float dx = __fsub_rn(__fmul_rn(__fadd_rn(bx, __fmul_rn(0.5f, bw)), Sf), colf);
        float dy = __fsub_rn(__fmul_rn(__fadd_rn(by, __fmul_rn(0.5f, bh)), Sf), rowf);
        dx = fminf(fmaxf(dx, 1e-6f), 0.999999f);
        dy = fminf(fmaxf(dy, 1e-6f), 0.999999f);
        float t0 = logf(__fdiv_rn(dx, __fsub_rn(1.0f, dx)));
        float t1 = logf(__fdiv_rn(dy, __fsub_rn(1.0f, dy)));
        float t2 = logf(__fdiv_rn(__fmul_rn(bw, 416.0f), c_awf[level][aa]));
        float t3 = logf(__fdiv_rn(__fmul_rn(bh, 416.0f), c_ahf[level][aa]));
        tcoord[gi] = make_float4(t0, t1, t2, t3);
        idxArr[gi] = sel;   // ordered after tid0's -1 via the barriers above
    }
}

// ---------------------------------------------------------------- fused loss
// blocks [0, OBJ_BLOCKS): obj BCE, one thread per (b,n); chosen/suppressed
//   recomputed on the fly (bit-identical IoU chain) — no winner/supp arrays.
// blocks [OBJ_BLOCKS, TOT_BLOCKS): coord+class for label gi, lane-parallel.
__global__ __launch_bounds__(256) void loss_kernel(
    const float* __restrict__ o0, const float* __restrict__ o1, const float* __restrict__ o2,
    const float* __restrict__ labels, const int* __restrict__ idxArr,
    const float4* __restrict__ tcoord,
    double* __restrict__ pObj, double* __restrict__ pCoord, double* __restrict__ pClass) {
    __shared__ float  s_box[2][LL][4];
    __shared__ float  s_cls[2][LL];
    __shared__ int    s_idx[2][LL];
    __shared__ double s_red[256];
    int tid = threadIdx.x;

    if (blockIdx.x < OBJ_BLOCKS) {
        int e0 = blockIdx.x * 256;
        int b0 = e0 / NPRI;
        int b1 = min((e0 + 255) / NPRI, BB - 1);
        for (int t = tid; t < 2 * LL; t += 256) {
            int which = t / LL, l = t - which * LL;
            int b = which ? b1 : b0;
            const float* lab = labels + (b * LL + l) * 5;
            s_cls[which][l]    = lab[0];
            s_box[which][l][0] = lab[1];
            s_box[which][l][1] = lab[2];
            s_box[which][l][2] = lab[3];
            s_box[which][l][3] = lab[4];
            s_idx[which][l]    = idxArr[b * LL + l];
        }
        __syncthreads();

        int e = e0 + tid;
        double a = 0.0;
        if (e < BB * NPRI) {
            int b = e / NPRI, n = e - b * NPRI;
            int which = (b == b0) ? 0 : 1;
            int level, S, ii, jj, aa, off;
            decode_prior(n, level, S, ii, jj, aa, off);
            double cxd = ((double)jj + 0.5) / (double)S;   // same rounding as assign's table
            double cyd = ((double)ii + 0.5) / (double)S;
            float px  = (float)(cxd - c_hw[level][aa]);
            float py  = (float)(cyd - c_hh[level][aa]);
            float pwf = c_pwf[level][aa], phf = c_phf[level][aa];
            float pxe = __fadd_rn(px, pwf), pye = __fadd_rn(py, phf);
            float pwph = __fmul_rn(pwf, phf);
            bool supp = false, chosen = false;
            for (int l = 0; l < LL; ++l) {
                if (s_cls[which][l] < 0.0f) continue;
                if (s_idx[which][l] == n) chosen = true;
                float bx = s_box[which][l][0], by = s_box[which][l][1];
                float bw = s_box[which][l][2], bh = s_box[which][l][3];
                float ix = fmaxf(px, bx), iy = fmaxf(py, by);
                float ax = fminf(pxe, __fadd_rn(bx, bw));
                float ay = fminf(pye, __fadd_rn(by, bh));
                float iw = fmaxf(__fsub_rn(ax, ix), 0.0f);
                float ih = fmaxf(__fsub_rn(ay, iy), 0.0f);
                float inter = __fmul_rn(iw, ih);
                float denom = __fsub_rn(__fadd_rn(pwph, __fmul_rn(bw, bh)), inter);
                float iou = __fdiv_rn(inter, denom);
                if (iou >= 0.5f) supp = true;
            }
            if (chosen || !supp) {   // masked-out entries contribute exactly 0
                int SS2 = S * S;
                const float* out = (level == 0) ? o0 : ((level == 1) ? o1 : o2);
                float x = out[(size_t)b * 255 * SS2 + (aa * 85 + 4) * SS2 + ii * S + jj];
                float p = 1.0f / (1.0f + expf(-x));
                float t = chosen ? 1.0f : 0.0f;
                float lp = fmaxf(logf(p), -100.0f);
                float lq = fmaxf(logf(1.0f - p), -100.0f);
                a = -(double)(t * lp + (1.0f - t) * lq) * c_wObj[level];
            }
        }
        s_red[tid] = a; __syncthreads();
        for (int s = 128; s > 0; s >>= 1) { if (tid < s) s_red[tid] += s_red[tid + s]; __syncthreads(); }
        if (tid == 0) pObj[blockIdx.x] = s_red[0];
    } else {
        int gi = blockIdx.x - OBJ_BLOCKS;
        int b  = gi / LL, lsel = gi - b * LL;
        if (tid < LL) {
            s_idx[0][tid] = idxArr[b * LL + tid];
            s_cls[0][tid] = labels[(b * LL + tid) * 5];
        }
        __syncthreads();
        int sel = s_idx[0][lsel];
        // winner = max label index mapping to sel (segment_max over g)
        int maxl = -1;
        if (sel >= 0)
            for (int l = 0; l < LL; ++l) if (s_idx[0][l] == sel) maxl = l;
        bool active = (sel >= 0) && (maxl == lsel);
        if (!active) {
            if (tid == 0) { pCoord[gi] = 0.0; pClass[gi] = 0.0; }
            return;   // uniform per block
        }
        int level, S, ii, jj, aa, off;
        decode_prior(sel, level, S, ii, jj, aa, off);
        int SS2 = S * S;
        const float* out = (level == 0) ? o0 : ((level == 1) ? o1 : o2);
        const float* base = out + (size_t)b * 255 * SS2 + aa * 85 * SS2 + ii * S + jj;
        double wObj = c_wObj[level];

        double val = 0.0;
        if (tid < 4) {                     // coord channels 0..3
            float4 ct = tcoord[gi];
            float ctk = (tid == 0) ? ct.x : (tid == 1) ? ct.y : (tid == 2) ? ct.z : ct.w;
            float x = base[tid * SS2];
            float d = __fsub_rn(x, ctk);
            val = (double)__fmul_rn(d, d) * (wObj * 0.25);
        } else if (tid >= 5 && tid < 85) { // class channels 5..84
            int cc = tid - 5;
            float x = base[tid * SS2];
            float t = 0.0f;
            for (int l = 0; l < LL; ++l)   // multi-hot over ALL labels mapping here
                if (s_idx[0][l] == sel && (int)s_cls[0][l] == cc) t = 1.0f;
            float p = 1.0f / (1.0f + expf(-x));
            float lp = fmaxf(logf(p), -100.0f);
            float lq = fmaxf(logf(1.0f - p), -100.0f);
            val = -(double)(t * lp + (1.0f - t) * lq) * (wObj * 0.0125);
        }
        s_red[tid] = (tid < 4) ? val : 0.0;
        __syncthreads();
        for (int s = 128; s > 0; s >>= 1) { if (tid < s) s_red[tid] += s_red[tid + s]; __syncthreads(); }
        if (tid == 0) pCoord[gi] = s_red[0];
        __syncthreads();
        s_red[tid] = (tid >= 5 && tid < 85) ? val : 0.0;
        __syncthreads();
        for (int s = 128; s > 0; s >>= 1) { if (tid < s) s_red[tid] += s_red[tid + s]; __syncthreads(); }
        if (tid == 0) pClass[gi] = s_red[0];
    }
}

// ---------------------------------------------------------------- finalize (1 block, no atomics)
__global__ __launch_bounds__(256) void finalize_kernel(
    const double* __restrict__ pObj, const double* __restrict__ pCoord,
    const double* __restrict__ pClass, float* __restrict__ out) {
    int tid = threadIdx.x;
    double sO = 0.0, sC = 0.0, sK = 0.0;
    for (int i = tid; i < OBJ_BLOCKS; i += 256) sO += pObj[i];
    for (int i = tid; i < CHO_BLOCKS; i += 256) { sC += pCoord[i]; sK += pClass[i]; }
    __shared__ double r0[256], r1[256], r2[256];
    r0[tid] = sO; r1[tid] = sC; r2[tid] = sK;
    __syncthreads();
    for (int s = 128; s > 0; s >>= 1) {
        if (tid < s) { r0[tid] += r0[tid + s]; r1[tid] += r1[tid + s]; r2[tid] += r2[tid + s]; }
        __syncthreads();
    }
    if (tid == 0) { out[0] = (float)r0[0]; out[1] = (float)r1[0]; out[2] = (float)r2[0]; }
}

extern "C" void kernel_launch(void* const* d_in, const int* in_sizes, int n_in,
                              void* d_out, int out_size, void* d_ws, size_t ws_size,
                              hipStream_t stream) {
    const float* o0     = (const float*)d_in[0];
    const float* o1     = (const float*)d_in[1];
    const float* o2     = (const float*)d_in[2];
    const float* labels = (const float*)d_in[3];

    char* ws = (char*)d_ws;
    int*    idxArr = (int*)   (ws);          // 800*4  = 3200
    float4* tcoord = (float4*)(ws + 3200);   // 800*16 -> 16000
    double* pObj   = (double*)(ws + 16000);  // 666*8  -> 21328
    double* pCoord = (double*)(ws + 21328);  // 800*8  -> 27728
    double* pClass = (double*)(ws + 27728);  // 800*8  -> 34128

    assign_kernel<<<BB * LL, 256, 0, stream>>>(labels, idxArr, tcoord);
    loss_kernel<<<TOT_BLOCKS, 256, 0, stream>>>(o0, o1, o2, labels, idxArr, tcoord,
                                                pObj, pCoord, pClass);
    finalize_kernel<<<1, 256, 0, stream>>>(pObj, pCoord, pClass, (float*)d_out);
}